// Round 10
// baseline (1052.964 us; speedup 1.0000x reference)
//
#include <hip/hip_runtime.h>

#define T_LEN 131072
#define RD 32
#define SD 512
#define QD 256
#define NL 27
#define KTOT (NL * RD)   // 864
#define GPAD 256         // guard rows (zeros) on each side of x buffers

typedef __attribute__((ext_vector_type(8))) short short8;
typedef __attribute__((ext_vector_type(4))) float floatx4;

__device__ __forceinline__ unsigned short f2bf(float f) {
    union { float f; unsigned int i; } v; v.f = f;
    unsigned int r = v.i + 0x7fffu + ((v.i >> 16) & 1u);  // RNE
    return (unsigned short)(r >> 16);
}

__device__ __forceinline__ float bf2f(unsigned short h) {
    union { unsigned int i; float f; } u; u.i = (unsigned int)h << 16;
    return u.f;
}

__device__ __forceinline__ void gload_lds16(const void* g, void* l) {
    __builtin_amdgcn_global_load_lds(
        (const __attribute__((address_space(1))) unsigned int*)g,
        (__attribute__((address_space(3))) unsigned int*)l, 16, 0, 0);
}

// ---------------- initial conv -> hi/lo bf16 split; zero ALL guards (hi+lo) ----------------
__global__ __launch_bounds__(256)
void k_conv_init(const float* __restrict__ x, const float* __restrict__ Wc,
                 const float* __restrict__ bc,
                 unsigned short* __restrict__ xahG, unsigned short* __restrict__ xalG,
                 unsigned short* __restrict__ xbhG, unsigned short* __restrict__ xblG)
{
    const int gid = blockIdx.x * 256 + threadIdx.x;

    // zero the 8 guard regions (pre/post of hi and lo for both buffers)
    if (gid < 8 * GPAD * RD) {
        const int region = gid >> 13;           // GPAD*RD = 8192
        const int idx = gid & (GPAD * RD - 1);
        unsigned short* hg;
        const size_t post = (size_t)(GPAD + T_LEN) * RD;
        switch (region) {
            case 0:  hg = xahG;        break;
            case 1:  hg = xahG + post; break;
            case 2:  hg = xbhG;        break;
            case 3:  hg = xbhG + post; break;
            case 4:  hg = xalG;        break;
            case 5:  hg = xalG + post; break;
            case 6:  hg = xblG;        break;
            default: hg = xblG + post; break;
        }
        hg[idx] = 0;
    }

    const int t = gid;
    const float xm = (t > 0) ? x[t - 1] : 0.f;
    const float x0 = x[t];
    const float xp = (t < T_LEN - 1) ? x[t + 1] : 0.f;
    unsigned short* rowh = xahG + (size_t)(GPAD + t) * RD;
    unsigned short* rowl = xalG + (size_t)(GPAD + t) * RD;
#pragma unroll
    for (int o = 0; o < RD; ++o) {
        const float v = bc[o] + Wc[o * 3 + 0] * xm + Wc[o * 3 + 1] * x0 + Wc[o * 3 + 2] * xp;
        const unsigned short h = f2bf(v);
        rowh[o] = h;
        rowl[o] = f2bf(v - bf2f(h));
    }
}

// ---------------- weight prep ----------------
__global__ __launch_bounds__(256)
void k_wprep(const float* __restrict__ Wt, const float* __restrict__ Ws,
             const float* __restrict__ Wd,
             unsigned short* __restrict__ Wg, unsigned short* __restrict__ Wdb)
{
    const int idx = blockIdx.x * 256 + threadIdx.x;
    const int n1 = NL * 64 * 96;
    const int n2 = NL * RD * RD;
    if (idx < n1) {
        const int l = idx / (64 * 96);
        const int rem = idx % (64 * 96);
        const int m = rem / 96;
        const int k = rem % 96;
        const int j = k / 32;
        const int c = k % 32;
        float v;
        if (m < 32) v = Wt[(((size_t)l * RD + m) * RD + c) * 3 + j];
        else        v = Ws[(((size_t)l * RD + (m - 32)) * RD + c) * 3 + j];
        Wg[idx] = f2bf(v);
    } else if (idx < n1 + n2) {
        const int i2 = idx - n1;
        Wdb[i2] = f2bf(Wd[i2]);
    }
}

// ---------------- 4-layer wave-local chain (d = 1,2,4,8), NO block barriers ----------------
// Each wave owns 32 rows and computes a 64-row extended window [t0-16, t0+48)
// through 4 layers. x carried in fp32 REGISTERS across layers; taps from
// wave-private LDS hi segs (ping-pong A/B); tap rows clamped to the window --
// clamp pollution provably never reaches the owned rows (cumulative halo 15,
// polluted rows stay in [-16,-2] u [+33,+48) rel., owned = [0,32)).
// Gt + final hi/lo stores predicated to owned rows (sets 1,2).
__global__ __launch_bounds__(256, 4)
void k_chain4(const unsigned short* __restrict__ xinh,   // guarded base + GPAD
              const unsigned short* __restrict__ xinl,
              unsigned short* __restrict__ xouth,
              unsigned short* __restrict__ xoutl,
              unsigned short* __restrict__ Gt,           // [NL][T][32]
              const unsigned short* __restrict__ WgAll,
              const unsigned short* __restrict__ WdbAll,
              const float* __restrict__ btAll,
              const float* __restrict__ bsAll,
              const float* __restrict__ bdAll,
              int l0)
{
    __shared__ unsigned short segA[4][64 * 32];   // 16 KB
    __shared__ unsigned short segB[4][64 * 32];   // 16 KB
    __shared__ unsigned short gsc[4][16 * 32];    // 4 KB  -> 36 KB total
    const int tid = threadIdx.x;
    const int lane = tid & 63;
    const int w = tid >> 6;
    const int quad = lane >> 4;
    const int l16 = lane & 15;
    const long long t0 = (long long)blockIdx.x * 128 + w * 32;
    const long long Wb = t0 - 16;                 // window base, 64 rows
    const floatx4 vzero = {0.f, 0.f, 0.f, 0.f};
    const int key2g = (l16 >> 1) & 3;

    // ---- stage input hi window into segA[w] (4 DMAs, pre-swizzled source) ----
    const int r16c = lane >> 2;
    const int scB = (lane & 3) ^ ((lane >> 3) & 3);
#pragma unroll
    for (int i = 0; i < 4; ++i)
        gload_lds16(xinh + (Wb + i * 16 + r16c) * RD + scB * 8,
                    &segA[w][(i * 16) * 32]);
    asm volatile("" ::: "memory");

    // ---- x fp32 regs for all 4 sets (hi+lo reconstruct, direct global reads) ----
    floatx4 x[4][2];
#pragma unroll
    for (int s = 0; s < 4; ++s) {
        const long long t = Wb + s * 16 + l16;
#pragma unroll
        for (int mt = 0; mt < 2; ++mt) {
            const ushort4 h4 = *reinterpret_cast<const ushort4*>(
                xinh + t * RD + mt * 16 + quad * 4);
            const ushort4 l4 = *reinterpret_cast<const ushort4*>(
                xinl + t * RD + mt * 16 + quad * 4);
            x[s][mt][0] = bf2f(h4.x) + bf2f(l4.x);
            x[s][mt][1] = bf2f(h4.y) + bf2f(l4.y);
            x[s][mt][2] = bf2f(h4.z) + bf2f(l4.z);
            x[s][mt][3] = bf2f(h4.w) + bf2f(l4.w);
        }
    }
    asm volatile("s_waitcnt vmcnt(0)" ::: "memory");  // segA + x loads complete

    static const int dd[4] = {1, 2, 4, 8};
#pragma unroll
    for (int k = 0; k < 4; ++k) {
        const int d = dd[k];
        const int l = l0 + k;
        const unsigned short* Wg = WgAll + (size_t)l * 64 * 96;
        const unsigned short* Wdb = WdbAll + (size_t)l * RD * RD;
        const float* btp = btAll + (size_t)l * RD;
        const float* bsp = bsAll + (size_t)l * RD;
        const float* bdp = bdAll + (size_t)l * RD;
        unsigned short* cur = (k & 1) ? segB[w] : segA[w];
        unsigned short* nxt = (k & 1) ? segA[w] : segB[w];

        short8 afr[3][4];
#pragma unroll
        for (int j = 0; j < 3; ++j)
#pragma unroll
            for (int mt = 0; mt < 4; ++mt)
                afr[j][mt] = *reinterpret_cast<const short8*>(
                    Wg + (size_t)(mt * 16 + l16) * 96 + j * 32 + quad * 8);
        short8 ad[2];
#pragma unroll
        for (int mt = 0; mt < 2; ++mt)
            ad[mt] = *reinterpret_cast<const short8*>(
                Wdb + (size_t)(mt * 16 + l16) * RD + quad * 8);

#pragma unroll
        for (int s = 0; s < 4; ++s) {
            // ---- phase A: gated conv, taps from cur seg (clamped rows) ----
            floatx4 acc[4];
#pragma unroll
            for (int mt = 0; mt < 4; ++mt) acc[mt] = vzero;
#pragma unroll
            for (int j = 0; j < 3; ++j) {
                int lr = s * 16 + l16 + (j - 1) * d;
                lr = lr < 0 ? 0 : (lr > 63 ? 63 : lr);
                const short8 bb = *reinterpret_cast<const short8*>(
                    &cur[lr * 32 + ((quad ^ ((lr >> 1) & 3)) * 8)]);
#pragma unroll
                for (int mt = 0; mt < 4; ++mt)
                    acc[mt] = __builtin_amdgcn_mfma_f32_16x16x32_bf16(
                        afr[j][mt], bb, acc[mt], 0, 0, 0);
            }

            // ---- gates -> gsc (wave-private) + Gt (owned rows) ----
            const bool owned = (s == 1 || s == 2);
            const long long tg = t0 + (long long)(s - 1) * 16 + l16;
#pragma unroll
            for (int pair = 0; pair < 2; ++pair) {
                const floatx4 bt4 = *reinterpret_cast<const floatx4*>(btp + pair * 16 + quad * 4);
                const floatx4 bs4 = *reinterpret_cast<const floatx4*>(bsp + pair * 16 + quad * 4);
                ushort4 u;
                unsigned short us[4];
#pragma unroll
                for (int r = 0; r < 4; ++r) {
                    const float a1 = acc[pair][r] + bt4[r];
                    const float a2 = acc[2 + pair][r] + bs4[r];
                    const float th = 1.f - __fdividef(2.f, __expf(2.f * a1) + 1.f);
                    const float sg = __fdividef(1.f, 1.f + __expf(-a2));
                    us[r] = f2bf(th * sg);
                }
                u.x = us[0]; u.y = us[1]; u.z = us[2]; u.w = us[3];
                const int colS = (pair * 2 + (quad >> 1)) ^ key2g;
                *reinterpret_cast<ushort4*>(
                    &gsc[w][l16 * 32 + colS * 8 + (quad & 1) * 4]) = u;
                if (owned)
                    *reinterpret_cast<ushort4*>(
                        Gt + ((size_t)l * T_LEN + tg) * RD + pair * 16 + quad * 4) = u;
            }
            asm volatile("s_waitcnt lgkmcnt(0)" ::: "memory");
            __builtin_amdgcn_sched_barrier(0);

            // ---- phase B: dense + residual (fp32 regs), hi to nxt seg ----
            const short8 bg = *reinterpret_cast<const short8*>(
                &gsc[w][l16 * 32 + (quad ^ key2g) * 8]);
            const int lrw = s * 16 + l16;
            const int key2w = (lrw >> 1) & 3;
#pragma unroll
            for (int mt = 0; mt < 2; ++mt) {
                const floatx4 a2v = __builtin_amdgcn_mfma_f32_16x16x32_bf16(
                    ad[mt], bg, vzero, 0, 0, 0);
                const floatx4 bd4 = *reinterpret_cast<const floatx4*>(bdp + mt * 16 + quad * 4);
                floatx4 xn;
                xn[0] = a2v[0] + bd4[0] + x[s][mt][0];
                xn[1] = a2v[1] + bd4[1] + x[s][mt][1];
                xn[2] = a2v[2] + bd4[2] + x[s][mt][2];
                xn[3] = a2v[3] + bd4[3] + x[s][mt][3];
                x[s][mt] = xn;
                ushort4 oh;
                oh.x = f2bf(xn[0]); oh.y = f2bf(xn[1]);
                oh.z = f2bf(xn[2]); oh.w = f2bf(xn[3]);
                if (k < 3) {
                    const int colS2 = (mt * 2 + (quad >> 1)) ^ key2w;
                    *reinterpret_cast<ushort4*>(
                        &nxt[lrw * 32 + colS2 * 8 + (quad & 1) * 4]) = oh;
                } else if (owned) {
                    ushort4 ol;
                    ol.x = f2bf(xn[0] - bf2f(oh.x));
                    ol.y = f2bf(xn[1] - bf2f(oh.y));
                    ol.z = f2bf(xn[2] - bf2f(oh.z));
                    ol.w = f2bf(xn[3] - bf2f(oh.w));
                    *reinterpret_cast<ushort4*>(xouth + tg * RD + mt * 16 + quad * 4) = oh;
                    *reinterpret_cast<ushort4*>(xoutl + tg * RD + mt * 16 + quad * 4) = ol;
                }
            }
            // WAR on gsc for next set + drain nxt writes before next layer's reads
            asm volatile("s_waitcnt lgkmcnt(0)" ::: "memory");
            __builtin_amdgcn_sched_barrier(0);
        }
    }
}

// ---------------- single residual layer (d>=16): per-wave async, NO barriers ----------------
__global__ __launch_bounds__(256, 4)
void k_layer_stage(const unsigned short* __restrict__ xinh,
                   const unsigned short* __restrict__ xinl,
                   unsigned short* __restrict__ xouth,
                   unsigned short* __restrict__ xoutl,
                   unsigned short* __restrict__ Gt,        // [NL][T][32]
                   const unsigned short* __restrict__ Wg,
                   const unsigned short* __restrict__ Wdb,
                   const float* __restrict__ bt, const float* __restrict__ bs,
                   const float* __restrict__ bd, int d, int layer)
{
    __shared__ unsigned short bandsL[3][128 * 32];  // 24 KB
    __shared__ unsigned short loL[128 * 32];        // 8 KB
    __shared__ unsigned short gtileL[128 * 32];     // 8 KB -> 40 KB total

    const int tid = threadIdx.x;
    const int lane = tid & 63;
    const int w = tid >> 6;
    const int quad = lane >> 4;
    const int l16 = lane & 15;
    const int rbase = w * 32;
    const bool last = (layer == NL - 1);
    const floatx4 vzero = {0.f, 0.f, 0.f, 0.f};

    const int r16c = lane >> 2;
    const int scB = (lane & 3) ^ ((lane >> 3) & 3);
    const long long gbase = (long long)blockIdx.x * 128 + rbase;

#pragma unroll
    for (int j = 0; j < 3; ++j) {
        const long long b0 = gbase + (long long)(j - 1) * d;
#pragma unroll
        for (int i = 0; i < 2; ++i)
            gload_lds16(xinh + (b0 + i * 16 + r16c) * RD + scB * 8,
                        &bandsL[j][(rbase + i * 16) * 32]);
    }
    asm volatile("" ::: "memory");
    if (!last) {
#pragma unroll
        for (int i = 0; i < 2; ++i)
            gload_lds16(xinl + (gbase + i * 16 + r16c) * RD + scB * 8,
                        &loL[(rbase + i * 16) * 32]);
        asm volatile("s_waitcnt vmcnt(2)" ::: "memory");
    } else {
        asm volatile("s_waitcnt vmcnt(0)" ::: "memory");
    }

    short8 afr[3][4];
#pragma unroll
    for (int j = 0; j < 3; ++j)
#pragma unroll
        for (int mt = 0; mt < 4; ++mt)
            afr[j][mt] = *reinterpret_cast<const short8*>(
                Wg + (size_t)(mt * 16 + l16) * 96 + j * 32 + quad * 8);

    floatx4 acc[4][2];
#pragma unroll
    for (int mt = 0; mt < 4; ++mt)
#pragma unroll
        for (int nt = 0; nt < 2; ++nt) acc[mt][nt] = vzero;

#pragma unroll
    for (int nt = 0; nt < 2; ++nt) {
        const int rloc = rbase + nt * 16 + l16;
        const int key2 = (rloc >> 1) & 3;
#pragma unroll
        for (int j = 0; j < 3; ++j) {
            const short8 bb = *reinterpret_cast<const short8*>(
                &bandsL[j][rloc * 32 + ((quad ^ key2) * 8)]);
#pragma unroll
            for (int mt = 0; mt < 4; ++mt)
                acc[mt][nt] = __builtin_amdgcn_mfma_f32_16x16x32_bf16(
                    afr[j][mt], bb, acc[mt][nt], 0, 0, 0);
        }
    }

    if (!last) asm volatile("s_waitcnt vmcnt(0)" ::: "memory");

#pragma unroll
    for (int nt = 0; nt < 2; ++nt) {
        const int rloc = rbase + nt * 16 + l16;
        const int key2 = (rloc >> 1) & 3;
        const long long t = (long long)blockIdx.x * 128 + rloc;
#pragma unroll
        for (int pair = 0; pair < 2; ++pair) {
            const floatx4 bt4 = *reinterpret_cast<const floatx4*>(bt + pair * 16 + quad * 4);
            const floatx4 bs4 = *reinterpret_cast<const floatx4*>(bs + pair * 16 + quad * 4);
            ushort4 u;
            unsigned short us[4];
#pragma unroll
            for (int r = 0; r < 4; ++r) {
                const float a1 = acc[pair][nt][r] + bt4[r];
                const float a2 = acc[2 + pair][nt][r] + bs4[r];
                const float th = 1.f - __fdividef(2.f, __expf(2.f * a1) + 1.f);
                const float sg = __fdividef(1.f, 1.f + __expf(-a2));
                us[r] = f2bf(th * sg);
            }
            u.x = us[0]; u.y = us[1]; u.z = us[2]; u.w = us[3];
            const int cbase = pair * 16 + quad * 4;
            if (!last) {
                const int colS = (pair * 2 + (quad >> 1)) ^ key2;
                *reinterpret_cast<ushort4*>(
                    &gtileL[rloc * 32 + colS * 8 + (quad & 1) * 4]) = u;
            }
            *reinterpret_cast<ushort4*>(
                Gt + ((size_t)layer * T_LEN + t) * RD + cbase) = u;
        }
    }

    if (!last) {
        short8 ad[2];
#pragma unroll
        for (int mt = 0; mt < 2; ++mt)
            ad[mt] = *reinterpret_cast<const short8*>(
                Wdb + (size_t)(mt * 16 + l16) * RD + quad * 8);

#pragma unroll
        for (int nt = 0; nt < 2; ++nt) {
            const int rloc = rbase + nt * 16 + l16;
            const int key2 = (rloc >> 1) & 3;
            const long long t = (long long)blockIdx.x * 128 + rloc;
            const short8 bg = *reinterpret_cast<const short8*>(
                &gtileL[rloc * 32 + ((quad ^ key2) * 8)]);
#pragma unroll
            for (int mt = 0; mt < 2; ++mt) {
                const floatx4 a2v = __builtin_amdgcn_mfma_f32_16x16x32_bf16(
                    ad[mt], bg, vzero, 0, 0, 0);
                const int m = mt * 16 + quad * 4;
                const int colS2 = (mt * 2 + (quad >> 1)) ^ key2;
                const int off = rloc * 32 + colS2 * 8 + (quad & 1) * 4;
                const ushort4 hi4 = *reinterpret_cast<const ushort4*>(&bandsL[1][off]);
                const ushort4 lo4 = *reinterpret_cast<const ushort4*>(&loL[off]);
                const floatx4 bd4 = *reinterpret_cast<const floatx4*>(bd + m);
                float o0 = a2v[0] + bd4[0] + bf2f(hi4.x) + bf2f(lo4.x);
                float o1 = a2v[1] + bd4[1] + bf2f(hi4.y) + bf2f(lo4.y);
                float o2 = a2v[2] + bd4[2] + bf2f(hi4.z) + bf2f(lo4.z);
                float o3 = a2v[3] + bd4[3] + bf2f(hi4.w) + bf2f(lo4.w);
                ushort4 oh, ol;
                oh.x = f2bf(o0); ol.x = f2bf(o0 - bf2f(oh.x));
                oh.y = f2bf(o1); ol.y = f2bf(o1 - bf2f(oh.y));
                oh.z = f2bf(o2); ol.z = f2bf(o2 - bf2f(oh.z));
                oh.w = f2bf(o3); ol.w = f2bf(o3 - bf2f(oh.w));
                *reinterpret_cast<ushort4*>(xouth + (size_t)t * RD + m) = oh;
                *reinterpret_cast<ushort4*>(xoutl + (size_t)t * RD + m) = ol;
            }
        }
    }
}

// ---------------- Wcomb (chunk-major [27][512][32]) ----------------
__global__ __launch_bounds__(256)
void k_wcomb(const float* __restrict__ Wp1, const float* __restrict__ Wskip,
             unsigned short* __restrict__ Wcomb)
{
    const int idx = blockIdx.x * 256 + threadIdx.x;
    if (idx >= SD * KTOT) return;
    const int m = idx / KTOT;
    const int k = idx % KTOT;
    const int l = k / RD;
    const int c = k % RD;
    const float* wp1r = Wp1 + (size_t)m * SD;
    const float* wsk = Wskip + (size_t)l * SD * RD + c;
    float acc = 0.f;
    for (int j = 0; j < SD; ++j) acc += wp1r[j] * wsk[(size_t)j * RD];
    Wcomb[((size_t)l * SD + m) * RD + c] = f2bf(acc);
}

// ---------------- hbias ----------------
__global__ __launch_bounds__(512)
void k_hbias(const float* __restrict__ Wp1, const float* __restrict__ bp1,
             const float* __restrict__ bskip, float* __restrict__ hbias)
{
    __shared__ float sb[SD];
    const int tid = threadIdx.x;
    float s = 0.f;
    for (int l = 0; l < NL; ++l) s += bskip[l * SD + tid];
    sb[tid] = s;
    __syncthreads();
    float acc = bp1[tid];
    const float* r = Wp1 + (size_t)tid * SD;
    for (int j = 0; j < SD; ++j) acc += r[j] * sb[j];
    hbias[tid] = acc;
}

// ---------------- fp32 -> bf16 cast ----------------
__global__ __launch_bounds__(256)
void k_cvt(const float* __restrict__ src, unsigned short* __restrict__ dst, int n)
{
    const int i = blockIdx.x * 256 + threadIdx.x;
    if (i < n) dst[i] = f2bf(src[i]);
}

// ---------------- GEMM1, BK=64 (known-good: 169 us) ----------------
__global__ __launch_bounds__(256)
void k_gemm1(const unsigned short* __restrict__ A,   // Wcomb [27][512][32]
             const unsigned short* __restrict__ B,   // Gt [27][T][32]
             const float* __restrict__ hbias,
             unsigned short* __restrict__ ht)        // [16][T][32]
{
    __shared__ unsigned short ldsA[2][128 * 32];  // 16 KB
    __shared__ unsigned short ldsB[2][128 * 32];  // 16 KB
    const int tid = threadIdx.x;
    const int lane = tid & 63;
    const int w = tid >> 6;
    const int wm = w & 1;
    const int wn = w >> 1;
    const int quad = lane >> 4;
    const int l16 = lane & 15;

    const int g = blockIdx.x;
    const int m0 = ((g >> 3) & 3) * 128;
    const int n0 = ((g & 7) + 8 * (g >> 5)) * 128;

    const int r4 = lane >> 2;
    const int c4 = lane & 3;
    const int srcc = c4 ^ ((r4 >> 1) & 3);
    const int swz = (l16 >> 1) & 3;

    floatx4 acc[4][4];
    const floatx4 vzero = {0.f, 0.f, 0.f, 0.f};
#pragma unroll
    for (int mt = 0; mt < 4; ++mt)
#pragma unroll
        for (int nt = 0; nt < 4; ++nt) acc[mt][nt] = vzero;

    const unsigned short* pA = A + (size_t)(m0 + r4) * RD + srcc * 8;
    const unsigned short* pB = B + (size_t)(n0 + r4) * RD + srcc * 8;

    for (int kc2 = 0; kc2 < 13; ++kc2) {
#pragma unroll
        for (int s = 0; s < 2; ++s) {
            const int kc = kc2 * 2 + s;
#pragma unroll
            for (int c = 0; c < 2; ++c) {
                const int row = w * 32 + c * 16;
                gload_lds16(pA + ((size_t)kc * SD + row) * RD, &ldsA[s][row * 32]);
                gload_lds16(pB + ((size_t)kc * T_LEN + row) * RD, &ldsB[s][row * 32]);
            }
        }
        __syncthreads();

#pragma unroll
        for (int s = 0; s < 2; ++s) {
            short8 afr[4], bfr[4];
#pragma unroll
            for (int mt = 0; mt < 4; ++mt)
                afr[mt] = *reinterpret_cast<const short8*>(
                    &ldsA[s][(wm * 64 + mt * 16 + l16) * 32 + (quad ^ swz) * 8]);
#pragma unroll
            for (int nt = 0; nt < 4; ++nt)
                bfr[nt] = *reinterpret_cast<const short8*>(
                    &ldsB[s][(wn * 64 + nt * 16 + l16) * 32 + (quad ^ swz) * 8]);
#pragma unroll
            for (int mt = 0; mt < 4; ++mt)
#pragma unroll
                for (int nt = 0; nt < 4; ++nt)
                    acc[mt][nt] = __builtin_amdgcn_mfma_f32_16x16x32_bf16(
                        afr[mt], bfr[nt], acc[mt][nt], 0, 0, 0);
        }
        __syncthreads();
    }
    // tail: chunk 26
    {
        const int kc = 26;
#pragma unroll
        for (int c = 0; c < 2; ++c) {
            const int row = w * 32 + c * 16;
            gload_lds16(pA + ((size_t)kc * SD + row) * RD, &ldsA[0][row * 32]);
            gload_lds16(pB + ((size_t)kc * T_LEN + row) * RD, &ldsB[0][row * 32]);
        }
        __syncthreads();
        short8 afr[4], bfr[4];
#pragma unroll
        for (int mt = 0; mt < 4; ++mt)
            afr[mt] = *reinterpret_cast<const short8*>(
                &ldsA[0][(wm * 64 + mt * 16 + l16) * 32 + (quad ^ swz) * 8]);
#pragma unroll
        for (int nt = 0; nt < 4; ++nt)
            bfr[nt] = *reinterpret_cast<const short8*>(
                &ldsB[0][(wn * 64 + nt * 16 + l16) * 32 + (quad ^ swz) * 8]);
#pragma unroll
        for (int mt = 0; mt < 4; ++mt)
#pragma unroll
            for (int nt = 0; nt < 4; ++nt)
                acc[mt][nt] = __builtin_amdgcn_mfma_f32_16x16x32_bf16(
                    afr[mt], bfr[nt], acc[mt][nt], 0, 0, 0);
    }

#pragma unroll
    for (int mt = 0; mt < 4; ++mt) {
        const int m = m0 + wm * 64 + mt * 16 + quad * 4;
        const floatx4 hb = *reinterpret_cast<const floatx4*>(hbias + m);
        const size_t chunkbase = (size_t)(m >> 5) * T_LEN;
        const int mc = m & 31;
#pragma unroll
        for (int nt = 0; nt < 4; ++nt) {
            const int t = n0 + wn * 64 + nt * 16 + l16;
            ushort4 st;
            float v;
            v = acc[mt][nt][0] + hb[0]; st.x = f2bf(v > 0.f ? v : 0.f);
            v = acc[mt][nt][1] + hb[1]; st.y = f2bf(v > 0.f ? v : 0.f);
            v = acc[mt][nt][2] + hb[2]; st.z = f2bf(v > 0.f ? v : 0.f);
            v = acc[mt][nt][3] + hb[3]; st.w = f2bf(v > 0.f ? v : 0.f);
            *reinterpret_cast<ushort4*>(ht + (chunkbase + t) * RD + mc) = st;
        }
    }
}

// ---------------- GEMM2 + fused log_softmax, 4-deep B staging ----------------
__global__ __launch_bounds__(256)
void k_gemm2_lsm(const unsigned short* __restrict__ A,  // Wp2b [256][512] bf16
                 const unsigned short* __restrict__ B,  // ht [16][T][32] bf16
                 const float* __restrict__ bp2,
                 float* __restrict__ out)               // [256][T] fp32
{
    __shared__ unsigned short ldsB[4][64 * 32];  // 16 KB
    __shared__ float redmax[4 * 16 * 16];
    __shared__ float redsum[4 * 16 * 16];
    const int tid = threadIdx.x;
    const int lane = tid & 63;
    const int w = tid >> 6;
    const int quad = lane >> 4;
    const int l16 = lane & 15;
    const int m0 = w * 64;
    const int n0 = blockIdx.x * 64;

    const int r4 = lane >> 2;
    const int c4 = lane & 3;
    const int srcc = c4 ^ ((r4 >> 1) & 3);
    const int swz = (l16 >> 1) & 3;

    const unsigned short* ab[4];
#pragma unroll
    for (int mt = 0; mt < 4; ++mt)
        ab[mt] = A + (size_t)(m0 + mt * 16 + l16) * SD + quad * 8;

    const unsigned short* pB = B + (size_t)(n0 + w * 16 + r4) * RD + srcc * 8;

    floatx4 acc[4][4];
    const floatx4 vzero = {0.f, 0.f, 0.f, 0.f};
#pragma unroll
    for (int mt = 0; mt < 4; ++mt)
#pragma unroll
        for (int nt = 0; nt < 4; ++nt) acc[mt][nt] = vzero;

    for (int kc4 = 0; kc4 < 4; ++kc4) {
#pragma unroll
        for (int s = 0; s < 4; ++s)
            gload_lds16(pB + (size_t)(kc4 * 4 + s) * T_LEN * RD,
                        &ldsB[s][(w * 16) * 32]);
        __syncthreads();

#pragma unroll
        for (int s = 0; s < 4; ++s) {
            const int kc = kc4 * 4 + s;
            short8 afr[4];
#pragma unroll
            for (int mt = 0; mt < 4; ++mt)
                afr[mt] = *reinterpret_cast<const short8*>(ab[mt] + kc * 32);
            short8 bfr[4];
#pragma unroll
            for (int nt = 0; nt < 4; ++nt)
                bfr[nt] = *reinterpret_cast<const short8*>(
                    &ldsB[s][(nt * 16 + l16) * 32 + (quad ^ swz) * 8]);
#pragma unroll
            for (int mt = 0; mt < 4; ++mt)
#pragma unroll
                for (int nt = 0; nt < 4; ++nt)
                    acc[mt][nt] = __builtin_amdgcn_mfma_f32_16x16x32_bf16(
                        afr[mt], bfr[nt], acc[mt][nt], 0, 0, 0);
        }
        __syncthreads();
    }

#pragma unroll
    for (int mt = 0; mt < 4; ++mt) {
        const int mb = m0 + mt * 16 + quad * 4;
        const floatx4 bz = *reinterpret_cast<const floatx4*>(bp2 + mb);
#pragma unroll
        for (int nt = 0; nt < 4; ++nt)
#pragma unroll
            for (int j = 0; j < 4; ++j) acc[mt][nt][j] += bz[j];
    }

#pragma unroll
    for (int nt = 0; nt < 4; ++nt) {
        float lm = -1e30f;
#pragma unroll
        for (int mt = 0; mt < 4; ++mt)
#pragma unroll
            for (int j = 0; j < 4; ++j) lm = fmaxf(lm, acc[mt][nt][j]);
        redmax[nt * 256 + l16 * 16 + w * 4 + quad] = lm;
    }
    __syncthreads();

    float lse[4];
#pragma unroll
    for (int nt = 0; nt < 4; ++nt) {
        float gm = -1e30f;
#pragma unroll
        for (int i = 0; i < 16; ++i) gm = fmaxf(gm, redmax[nt * 256 + l16 * 16 + i]);
        float ls = 0.f;
#pragma unroll
        for (int mt = 0; mt < 4; ++mt)
#pragma unroll
            for (int j = 0; j < 4; ++j) ls += __expf(acc[mt][nt][j] - gm);
        redsum[nt * 256 + l16 * 16 + w * 4 + quad] = ls;
        lse[nt] = gm;
    }
    __syncthreads();

#pragma unroll
    for (int nt = 0; nt < 4; ++nt) {
        float tot = 0.f;
#pragma unroll
        for (int i = 0; i < 16; ++i) tot += redsum[nt * 256 + l16 * 16 + i];
        lse[nt] = lse[nt] + __logf(tot);
    }

#pragma unroll
    for (int mt = 0; mt < 4; ++mt) {
        const int mb = m0 + mt * 16 + quad * 4;
#pragma unroll
        for (int nt = 0; nt < 4; ++nt) {
            const int t = n0 + nt * 16 + l16;
#pragma unroll
            for (int j = 0; j < 4; ++j)
                out[(size_t)(mb + j) * T_LEN + t] = acc[mt][nt][j] - lse[nt];
        }
    }
}

extern "C" void kernel_launch(void* const* d_in, const int* in_sizes, int n_in,
                              void* d_out, int out_size, void* d_ws, size_t ws_size,
                              hipStream_t stream)
{
    (void)in_sizes; (void)n_in; (void)out_size; (void)ws_size;
    const float* x     = (const float*)d_in[0];
    const float* Wc    = (const float*)d_in[1];
    const float* bc    = (const float*)d_in[2];
    const float* Wt    = (const float*)d_in[3];
    const float* bt    = (const float*)d_in[4];
    const float* Ws    = (const float*)d_in[5];
    const float* bs    = (const float*)d_in[6];
    const float* Wskip = (const float*)d_in[7];
    const float* bskip = (const float*)d_in[8];
    const float* Wd    = (const float*)d_in[9];
    const float* bd    = (const float*)d_in[10];
    const float* Wp1   = (const float*)d_in[11];
    const float* bp1   = (const float*)d_in[12];
    const float* Wp2   = (const float*)d_in[13];
    const float* bp2   = (const float*)d_in[14];
    float* out = (float*)d_out;

    char* p = (char*)d_ws;
    unsigned short* Gt = (unsigned short*)p;    p += (size_t)T_LEN * KTOT * 2;   // 226.5 MB
    unsigned short* ht = (unsigned short*)p;    p += (size_t)T_LEN * SD * 2;     // 134 MB
    unsigned short* Wcomb = (unsigned short*)p; p += (size_t)SD * KTOT * 2;
    unsigned short* Wp2b = (unsigned short*)p;  p += (size_t)QD * SD * 2;
    unsigned short* Wg = (unsigned short*)p;    p += (size_t)NL * 64 * 96 * 2;
    unsigned short* Wdb = (unsigned short*)p;   p += (size_t)NL * RD * RD * 2;
    float* hbias = (float*)p;                   p += (size_t)SD * 4;

    // guarded hi/lo x buffers alias the ht region (dead before gemm1 writes ht)
    char* q = (char*)ht;
    const size_t grows = (size_t)(T_LEN + 2 * GPAD) * RD;
    unsigned short* xahG = (unsigned short*)q;  q += grows * 2;
    unsigned short* xalG = (unsigned short*)q;  q += grows * 2;
    unsigned short* xbhG = (unsigned short*)q;  q += grows * 2;
    unsigned short* xblG = (unsigned short*)q;  q += grows * 2;
    unsigned short* xah = xahG + (size_t)GPAD * RD;
    unsigned short* xal = xalG + (size_t)GPAD * RD;
    unsigned short* xbh = xbhG + (size_t)GPAD * RD;
    unsigned short* xbl = xblG + (size_t)GPAD * RD;

    k_wcomb<<<(SD * KTOT + 255) / 256, 256, 0, stream>>>(Wp1, Wskip, Wcomb);
    k_hbias<<<1, 512, 0, stream>>>(Wp1, bp1, bskip, hbias);
    k_cvt<<<(QD * SD + 255) / 256, 256, 0, stream>>>(Wp2, Wp2b, QD * SD);
    {
        const int nprep = NL * 64 * 96 + NL * RD * RD;
        k_wprep<<<(nprep + 255) / 256, 256, 0, stream>>>(Wt, Ws, Wd, Wg, Wdb);
    }
    k_conv_init<<<T_LEN / 256, 256, 0, stream>>>(x, Wc, bc, xahG, xalG, xbhG, xblG);

    const unsigned short* curh = xah;
    const unsigned short* curl = xal;
    unsigned short* nxth = xbh;
    unsigned short* nxtl = xbl;
    static const int dsing[5] = {16, 32, 64, 128, 256};
    for (int s = 0; s < 3; ++s) {
        // layers 9s .. 9s+3 (d = 1,2,4,8) fused wave-locally
        k_chain4<<<T_LEN / 128, 256, 0, stream>>>(
            curh, curl, nxth, nxtl, Gt, Wg, Wdb, bt, bs, bd, 9 * s);
        { unsigned short* th = (unsigned short*)curh; curh = nxth; nxth = th; }
        { unsigned short* tl = (unsigned short*)curl; curl = nxtl; nxtl = tl; }
        // layers 9s+4 .. 9s+8 (d = 16..256) single
        for (int j = 0; j < 5; ++j) {
            const int li = 9 * s + 4 + j;
            k_layer_stage<<<T_LEN / 128, 256, 0, stream>>>(
                curh, curl, nxth, nxtl, Gt,
                Wg + (size_t)li * 64 * 96,
                Wdb + (size_t)li * RD * RD,
                bt + (size_t)li * RD,
                bs + (size_t)li * RD,
                bd + (size_t)li * RD,
                dsing[j], li);
            { unsigned short* th = (unsigned short*)curh; curh = nxth; nxth = th; }
            { unsigned short* tl = (unsigned short*)curl; curl = nxtl; nxtl = tl; }
        }
    }

    k_gemm1<<<4 * (T_LEN / 128), 256, 0, stream>>>(Wcomb, Gt, hbias, ht);
    k_gemm2_lsm<<<T_LEN / 64, 256, 0, stream>>>(Wp2b, ht, bp2, out);
}

// Round 11
// 895.586 us; speedup vs baseline: 1.1757x; 1.1757x over previous
//
#include <hip/hip_runtime.h>

#define T_LEN 131072
#define RD 32
#define SD 512
#define QD 256
#define NL 27
#define KTOT (NL * RD)   // 864
#define GPAD 256         // guard rows (zeros) on each side of x-hi buffers

typedef __attribute__((ext_vector_type(8))) short short8;
typedef __attribute__((ext_vector_type(4))) float floatx4;

__device__ __forceinline__ unsigned short f2bf(float f) {
    union { float f; unsigned int i; } v; v.f = f;
    unsigned int r = v.i + 0x7fffu + ((v.i >> 16) & 1u);  // RNE
    return (unsigned short)(r >> 16);
}

__device__ __forceinline__ float bf2f(unsigned short h) {
    union { unsigned int i; float f; } u; u.i = (unsigned int)h << 16;
    return u.f;
}

__device__ __forceinline__ void gload_lds16(const void* g, void* l) {
    __builtin_amdgcn_global_load_lds(
        (const __attribute__((address_space(1))) unsigned int*)g,
        (__attribute__((address_space(3))) unsigned int*)l, 16, 0, 0);
}

// ---------------- initial conv: [1,T] -> hi/lo bf16 split; zero hi guards ----------------
// x is carried as hi (bf16 RNE of x -- also the MFMA tap operand) + lo
// (bf16 of the remainder). hi+lo == x to ~2^-17 relative; taps bit-identical
// to the old fp32+mirror scheme.
__global__ __launch_bounds__(256)
void k_conv_init(const float* __restrict__ x, const float* __restrict__ Wc,
                 const float* __restrict__ bc,
                 unsigned short* __restrict__ xahG, unsigned short* __restrict__ xalG,
                 unsigned short* __restrict__ xbhG)
{
    const int gid = blockIdx.x * 256 + threadIdx.x;

    // zero the hi-array guard regions (taps read them; zeros == conv padding)
    if (gid < 4 * GPAD * RD) {
        const int region = gid >> 13;           // GPAD*RD = 8192
        const int idx = gid & (GPAD * RD - 1);
        unsigned short* hg;
        const size_t post = (size_t)(GPAD + T_LEN) * RD;
        switch (region) {
            case 0:  hg = xahG;        break;
            case 1:  hg = xahG + post; break;
            case 2:  hg = xbhG;        break;
            default: hg = xbhG + post; break;
        }
        hg[idx] = 0;
    }

    const int t = gid;
    const float xm = (t > 0) ? x[t - 1] : 0.f;
    const float x0 = x[t];
    const float xp = (t < T_LEN - 1) ? x[t + 1] : 0.f;
    unsigned short* rowh = xahG + (size_t)(GPAD + t) * RD;
    unsigned short* rowl = xalG + (size_t)(GPAD + t) * RD;
#pragma unroll
    for (int o = 0; o < RD; ++o) {
        const float v = bc[o] + Wc[o * 3 + 0] * xm + Wc[o * 3 + 1] * x0 + Wc[o * 3 + 2] * xp;
        const unsigned short h = f2bf(v);
        rowh[o] = h;
        rowl[o] = f2bf(v - bf2f(h));
    }
}

// ---------------- weight prep ----------------
__global__ __launch_bounds__(256)
void k_wprep(const float* __restrict__ Wt, const float* __restrict__ Ws,
             const float* __restrict__ Wd,
             unsigned short* __restrict__ Wg, unsigned short* __restrict__ Wdb)
{
    const int idx = blockIdx.x * 256 + threadIdx.x;
    const int n1 = NL * 64 * 96;
    const int n2 = NL * RD * RD;
    if (idx < n1) {
        const int l = idx / (64 * 96);
        const int rem = idx % (64 * 96);
        const int m = rem / 96;
        const int k = rem % 96;
        const int j = k / 32;
        const int c = k % 32;
        float v;
        if (m < 32) v = Wt[(((size_t)l * RD + m) * RD + c) * 3 + j];
        else        v = Ws[(((size_t)l * RD + (m - 32)) * RD + c) * 3 + j];
        Wg[idx] = f2bf(v);
    } else if (idx < n1 + n2) {
        const int i2 = idx - n1;
        Wdb[i2] = f2bf(Wd[i2]);
    }
}

// ---------------- single residual layer: hi/lo bf16 x, per-wave async, NO barriers ----------------
// Per wave: DMA 3 hi tap bands (6) + 1 lo center band (2). vmcnt(2) -> bands
// ready, phase A from LDS. vmcnt(0) -> lo ready; phase B reconstructs
// x = bf2f(hi_center) + bf2f(lo) from LDS (hi center band == band j=1),
// adds dense+bias, re-splits to hi/lo and stores. fp32 x array eliminated:
// handoff = 25.2 MB/layer (was 33.6 write + 25.2 read).
__global__ __launch_bounds__(256, 4)
void k_layer_stage(const unsigned short* __restrict__ xinh,   // guarded + GPAD
                   const unsigned short* __restrict__ xinl,   // + GPAD (rows [0,T) used)
                   unsigned short* __restrict__ xouth,
                   unsigned short* __restrict__ xoutl,
                   unsigned short* __restrict__ Gt,           // [NL][T][32]
                   const unsigned short* __restrict__ Wg,
                   const unsigned short* __restrict__ Wdb,
                   const float* __restrict__ bt, const float* __restrict__ bs,
                   const float* __restrict__ bd, int d, int layer)
{
    __shared__ unsigned short bandsL[3][128 * 32];  // 24 KB (hi taps)
    __shared__ unsigned short loL[128 * 32];        // 8 KB (lo center)
    __shared__ unsigned short gtileL[128 * 32];     // 8 KB -> 40 KB total

    const int tid = threadIdx.x;
    const int lane = tid & 63;
    const int w = tid >> 6;
    const int quad = lane >> 4;
    const int l16 = lane & 15;
    const int rbase = w * 32;
    const bool last = (layer == NL - 1);
    const floatx4 vzero = {0.f, 0.f, 0.f, 0.f};

    const int r16c = lane >> 2;
    const int scB = (lane & 3) ^ ((lane >> 3) & 3);
    const long long gbase = (long long)blockIdx.x * 128 + rbase;

    // ---- issue hi band DMAs (6) ----
#pragma unroll
    for (int j = 0; j < 3; ++j) {
        const long long b0 = gbase + (long long)(j - 1) * d;
#pragma unroll
        for (int i = 0; i < 2; ++i)
            gload_lds16(xinh + (b0 + i * 16 + r16c) * RD + scB * 8,
                        &bandsL[j][(rbase + i * 16) * 32]);
    }
    asm volatile("" ::: "memory");   // pin: bands issue before lo DMAs

    // ---- issue lo center DMAs (2) + counted wait ----
    if (!last) {
#pragma unroll
        for (int i = 0; i < 2; ++i)
            gload_lds16(xinl + (gbase + i * 16 + r16c) * RD + scB * 8,
                        &loL[(rbase + i * 16) * 32]);
        asm volatile("s_waitcnt vmcnt(2)" ::: "memory");  // 6 bands done, lo in flight
    } else {
        asm volatile("s_waitcnt vmcnt(0)" ::: "memory");
    }

    short8 afr[3][4];
#pragma unroll
    for (int j = 0; j < 3; ++j)
#pragma unroll
        for (int mt = 0; mt < 4; ++mt)
            afr[j][mt] = *reinterpret_cast<const short8*>(
                Wg + (size_t)(mt * 16 + l16) * 96 + j * 32 + quad * 8);

    floatx4 acc[4][2];
#pragma unroll
    for (int mt = 0; mt < 4; ++mt)
#pragma unroll
        for (int nt = 0; nt < 2; ++nt) acc[mt][nt] = vzero;

#pragma unroll
    for (int nt = 0; nt < 2; ++nt) {
        const int rloc = rbase + nt * 16 + l16;
        const int key2 = (rloc >> 1) & 3;
#pragma unroll
        for (int j = 0; j < 3; ++j) {
            const short8 bb = *reinterpret_cast<const short8*>(
                &bandsL[j][rloc * 32 + ((quad ^ key2) * 8)]);
#pragma unroll
            for (int mt = 0; mt < 4; ++mt)
                acc[mt][nt] = __builtin_amdgcn_mfma_f32_16x16x32_bf16(
                    afr[j][mt], bb, acc[mt][nt], 0, 0, 0);
        }
    }

    if (!last) asm volatile("s_waitcnt vmcnt(0)" ::: "memory");  // lo ready

#pragma unroll
    for (int nt = 0; nt < 2; ++nt) {
        const int rloc = rbase + nt * 16 + l16;
        const int key2 = (rloc >> 1) & 3;
        const long long t = (long long)blockIdx.x * 128 + rloc;
#pragma unroll
        for (int pair = 0; pair < 2; ++pair) {
            const floatx4 bt4 = *reinterpret_cast<const floatx4*>(bt + pair * 16 + quad * 4);
            const floatx4 bs4 = *reinterpret_cast<const floatx4*>(bs + pair * 16 + quad * 4);
            ushort4 u;
            unsigned short us[4];
#pragma unroll
            for (int r = 0; r < 4; ++r) {
                const float a1 = acc[pair][nt][r] + bt4[r];
                const float a2 = acc[2 + pair][nt][r] + bs4[r];
                const float th = 1.f - __fdividef(2.f, __expf(2.f * a1) + 1.f);
                const float sg = __fdividef(1.f, 1.f + __expf(-a2));
                us[r] = f2bf(th * sg);
            }
            u.x = us[0]; u.y = us[1]; u.z = us[2]; u.w = us[3];
            const int cbase = pair * 16 + quad * 4;
            if (!last) {
                const int colS = (pair * 2 + (quad >> 1)) ^ key2;
                *reinterpret_cast<ushort4*>(
                    &gtileL[rloc * 32 + colS * 8 + (quad & 1) * 4]) = u;
            }
            *reinterpret_cast<ushort4*>(
                Gt + ((size_t)layer * T_LEN + t) * RD + cbase) = u;
        }
    }

    if (!last) {
        short8 ad[2];
#pragma unroll
        for (int mt = 0; mt < 2; ++mt)
            ad[mt] = *reinterpret_cast<const short8*>(
                Wdb + (size_t)(mt * 16 + l16) * RD + quad * 8);

#pragma unroll
        for (int nt = 0; nt < 2; ++nt) {
            const int rloc = rbase + nt * 16 + l16;
            const int key2 = (rloc >> 1) & 3;
            const long long t = (long long)blockIdx.x * 128 + rloc;
            const short8 bg = *reinterpret_cast<const short8*>(
                &gtileL[rloc * 32 + ((quad ^ key2) * 8)]);
#pragma unroll
            for (int mt = 0; mt < 2; ++mt) {
                const floatx4 a2v = __builtin_amdgcn_mfma_f32_16x16x32_bf16(
                    ad[mt], bg, vzero, 0, 0, 0);
                const int m = mt * 16 + quad * 4;
                // hi center == band j=1; lo from loL; same chunk addressing as gtile
                const int colS2 = (mt * 2 + (quad >> 1)) ^ key2;
                const int off = rloc * 32 + colS2 * 8 + (quad & 1) * 4;
                const ushort4 hi4 = *reinterpret_cast<const ushort4*>(&bandsL[1][off]);
                const ushort4 lo4 = *reinterpret_cast<const ushort4*>(&loL[off]);
                const floatx4 bd4 = *reinterpret_cast<const floatx4*>(bd + m);
                float o0 = a2v[0] + bd4[0] + bf2f(hi4.x) + bf2f(lo4.x);
                float o1 = a2v[1] + bd4[1] + bf2f(hi4.y) + bf2f(lo4.y);
                float o2 = a2v[2] + bd4[2] + bf2f(hi4.z) + bf2f(lo4.z);
                float o3 = a2v[3] + bd4[3] + bf2f(hi4.w) + bf2f(lo4.w);
                ushort4 oh, ol;
                oh.x = f2bf(o0); ol.x = f2bf(o0 - bf2f(oh.x));
                oh.y = f2bf(o1); ol.y = f2bf(o1 - bf2f(oh.y));
                oh.z = f2bf(o2); ol.z = f2bf(o2 - bf2f(oh.z));
                oh.w = f2bf(o3); ol.w = f2bf(o3 - bf2f(oh.w));
                *reinterpret_cast<ushort4*>(xouth + (size_t)t * RD + m) = oh;
                *reinterpret_cast<ushort4*>(xoutl + (size_t)t * RD + m) = ol;
            }
        }
    }
}

// ---------------- Wcomb (chunk-major [27][512][32]) ----------------
__global__ __launch_bounds__(256)
void k_wcomb(const float* __restrict__ Wp1, const float* __restrict__ Wskip,
             unsigned short* __restrict__ Wcomb)
{
    const int idx = blockIdx.x * 256 + threadIdx.x;
    if (idx >= SD * KTOT) return;
    const int m = idx / KTOT;
    const int k = idx % KTOT;
    const int l = k / RD;
    const int c = k % RD;
    const float* wp1r = Wp1 + (size_t)m * SD;
    const float* wsk = Wskip + (size_t)l * SD * RD + c;
    float acc = 0.f;
    for (int j = 0; j < SD; ++j) acc += wp1r[j] * wsk[(size_t)j * RD];
    Wcomb[((size_t)l * SD + m) * RD + c] = f2bf(acc);
}

// ---------------- hbias ----------------
__global__ __launch_bounds__(512)
void k_hbias(const float* __restrict__ Wp1, const float* __restrict__ bp1,
             const float* __restrict__ bskip, float* __restrict__ hbias)
{
    __shared__ float sb[SD];
    const int tid = threadIdx.x;
    float s = 0.f;
    for (int l = 0; l < NL; ++l) s += bskip[l * SD + tid];
    sb[tid] = s;
    __syncthreads();
    float acc = bp1[tid];
    const float* r = Wp1 + (size_t)tid * SD;
    for (int j = 0; j < SD; ++j) acc += r[j] * sb[j];
    hbias[tid] = acc;
}

// ---------------- fp32 -> bf16 cast ----------------
__global__ __launch_bounds__(256)
void k_cvt(const float* __restrict__ src, unsigned short* __restrict__ dst, int n)
{
    const int i = blockIdx.x * 256 + threadIdx.x;
    if (i < n) dst[i] = f2bf(src[i]);
}

// ---------------- GEMM1, BK=64 (R6/R8 known-good: 169 us) ----------------
__global__ __launch_bounds__(256)
void k_gemm1(const unsigned short* __restrict__ A,   // Wcomb [27][512][32]
             const unsigned short* __restrict__ B,   // Gt [27][T][32]
             const float* __restrict__ hbias,
             unsigned short* __restrict__ ht)        // [16][T][32]
{
    __shared__ unsigned short ldsA[2][128 * 32];  // 16 KB
    __shared__ unsigned short ldsB[2][128 * 32];  // 16 KB
    const int tid = threadIdx.x;
    const int lane = tid & 63;
    const int w = tid >> 6;
    const int wm = w & 1;
    const int wn = w >> 1;
    const int quad = lane >> 4;
    const int l16 = lane & 15;

    const int g = blockIdx.x;
    const int m0 = ((g >> 3) & 3) * 128;
    const int n0 = ((g & 7) + 8 * (g >> 5)) * 128;

    const int r4 = lane >> 2;
    const int c4 = lane & 3;
    const int srcc = c4 ^ ((r4 >> 1) & 3);
    const int swz = (l16 >> 1) & 3;

    floatx4 acc[4][4];
    const floatx4 vzero = {0.f, 0.f, 0.f, 0.f};
#pragma unroll
    for (int mt = 0; mt < 4; ++mt)
#pragma unroll
        for (int nt = 0; nt < 4; ++nt) acc[mt][nt] = vzero;

    const unsigned short* pA = A + (size_t)(m0 + r4) * RD + srcc * 8;
    const unsigned short* pB = B + (size_t)(n0 + r4) * RD + srcc * 8;

    for (int kc2 = 0; kc2 < 13; ++kc2) {
#pragma unroll
        for (int s = 0; s < 2; ++s) {
            const int kc = kc2 * 2 + s;
#pragma unroll
            for (int c = 0; c < 2; ++c) {
                const int row = w * 32 + c * 16;
                gload_lds16(pA + ((size_t)kc * SD + row) * RD, &ldsA[s][row * 32]);
                gload_lds16(pB + ((size_t)kc * T_LEN + row) * RD, &ldsB[s][row * 32]);
            }
        }
        __syncthreads();

#pragma unroll
        for (int s = 0; s < 2; ++s) {
            short8 afr[4], bfr[4];
#pragma unroll
            for (int mt = 0; mt < 4; ++mt)
                afr[mt] = *reinterpret_cast<const short8*>(
                    &ldsA[s][(wm * 64 + mt * 16 + l16) * 32 + (quad ^ swz) * 8]);
#pragma unroll
            for (int nt = 0; nt < 4; ++nt)
                bfr[nt] = *reinterpret_cast<const short8*>(
                    &ldsB[s][(wn * 64 + nt * 16 + l16) * 32 + (quad ^ swz) * 8]);
#pragma unroll
            for (int mt = 0; mt < 4; ++mt)
#pragma unroll
                for (int nt = 0; nt < 4; ++nt)
                    acc[mt][nt] = __builtin_amdgcn_mfma_f32_16x16x32_bf16(
                        afr[mt], bfr[nt], acc[mt][nt], 0, 0, 0);
        }
        __syncthreads();
    }
    // tail: chunk 26
    {
        const int kc = 26;
#pragma unroll
        for (int c = 0; c < 2; ++c) {
            const int row = w * 32 + c * 16;
            gload_lds16(pA + ((size_t)kc * SD + row) * RD, &ldsA[0][row * 32]);
            gload_lds16(pB + ((size_t)kc * T_LEN + row) * RD, &ldsB[0][row * 32]);
        }
        __syncthreads();
        short8 afr[4], bfr[4];
#pragma unroll
        for (int mt = 0; mt < 4; ++mt)
            afr[mt] = *reinterpret_cast<const short8*>(
                &ldsA[0][(wm * 64 + mt * 16 + l16) * 32 + (quad ^ swz) * 8]);
#pragma unroll
        for (int nt = 0; nt < 4; ++nt)
            bfr[nt] = *reinterpret_cast<const short8*>(
                &ldsB[0][(wn * 64 + nt * 16 + l16) * 32 + (quad ^ swz) * 8]);
#pragma unroll
        for (int mt = 0; mt < 4; ++mt)
#pragma unroll
            for (int nt = 0; nt < 4; ++nt)
                acc[mt][nt] = __builtin_amdgcn_mfma_f32_16x16x32_bf16(
                    afr[mt], bfr[nt], acc[mt][nt], 0, 0, 0);
    }

#pragma unroll
    for (int mt = 0; mt < 4; ++mt) {
        const int m = m0 + wm * 64 + mt * 16 + quad * 4;
        const floatx4 hb = *reinterpret_cast<const floatx4*>(hbias + m);
        const size_t chunkbase = (size_t)(m >> 5) * T_LEN;
        const int mc = m & 31;
#pragma unroll
        for (int nt = 0; nt < 4; ++nt) {
            const int t = n0 + wn * 64 + nt * 16 + l16;
            ushort4 st;
            float v;
            v = acc[mt][nt][0] + hb[0]; st.x = f2bf(v > 0.f ? v : 0.f);
            v = acc[mt][nt][1] + hb[1]; st.y = f2bf(v > 0.f ? v : 0.f);
            v = acc[mt][nt][2] + hb[2]; st.z = f2bf(v > 0.f ? v : 0.f);
            v = acc[mt][nt][3] + hb[3]; st.w = f2bf(v > 0.f ? v : 0.f);
            *reinterpret_cast<ushort4*>(ht + (chunkbase + t) * RD + mc) = st;
        }
    }
}

// ---------------- GEMM2 + fused log_softmax, 4-deep B staging (R7/R8: kept) ----------------
__global__ __launch_bounds__(256)
void k_gemm2_lsm(const unsigned short* __restrict__ A,  // Wp2b [256][512] bf16
                 const unsigned short* __restrict__ B,  // ht [16][T][32] bf16
                 const float* __restrict__ bp2,
                 float* __restrict__ out)               // [256][T] fp32
{
    __shared__ unsigned short ldsB[4][64 * 32];  // 16 KB
    __shared__ float redmax[4 * 16 * 16];
    __shared__ float redsum[4 * 16 * 16];
    const int tid = threadIdx.x;
    const int lane = tid & 63;
    const int w = tid >> 6;
    const int quad = lane >> 4;
    const int l16 = lane & 15;
    const int m0 = w * 64;
    const int n0 = blockIdx.x * 64;

    const int r4 = lane >> 2;
    const int c4 = lane & 3;
    const int srcc = c4 ^ ((r4 >> 1) & 3);
    const int swz = (l16 >> 1) & 3;

    const unsigned short* ab[4];
#pragma unroll
    for (int mt = 0; mt < 4; ++mt)
        ab[mt] = A + (size_t)(m0 + mt * 16 + l16) * SD + quad * 8;

    const unsigned short* pB = B + (size_t)(n0 + w * 16 + r4) * RD + srcc * 8;

    floatx4 acc[4][4];
    const floatx4 vzero = {0.f, 0.f, 0.f, 0.f};
#pragma unroll
    for (int mt = 0; mt < 4; ++mt)
#pragma unroll
        for (int nt = 0; nt < 4; ++nt) acc[mt][nt] = vzero;

    for (int kc4 = 0; kc4 < 4; ++kc4) {
#pragma unroll
        for (int s = 0; s < 4; ++s)
            gload_lds16(pB + (size_t)(kc4 * 4 + s) * T_LEN * RD,
                        &ldsB[s][(w * 16) * 32]);
        __syncthreads();

#pragma unroll
        for (int s = 0; s < 4; ++s) {
            const int kc = kc4 * 4 + s;
            short8 afr[4];
#pragma unroll
            for (int mt = 0; mt < 4; ++mt)
                afr[mt] = *reinterpret_cast<const short8*>(ab[mt] + kc * 32);
            short8 bfr[4];
#pragma unroll
            for (int nt = 0; nt < 4; ++nt)
                bfr[nt] = *reinterpret_cast<const short8*>(
                    &ldsB[s][(nt * 16 + l16) * 32 + (quad ^ swz) * 8]);
#pragma unroll
            for (int mt = 0; mt < 4; ++mt)
#pragma unroll
                for (int nt = 0; nt < 4; ++nt)
                    acc[mt][nt] = __builtin_amdgcn_mfma_f32_16x16x32_bf16(
                        afr[mt], bfr[nt], acc[mt][nt], 0, 0, 0);
        }
        __syncthreads();
    }

#pragma unroll
    for (int mt = 0; mt < 4; ++mt) {
        const int mb = m0 + mt * 16 + quad * 4;
        const floatx4 bz = *reinterpret_cast<const floatx4*>(bp2 + mb);
#pragma unroll
        for (int nt = 0; nt < 4; ++nt)
#pragma unroll
            for (int j = 0; j < 4; ++j) acc[mt][nt][j] += bz[j];
    }

#pragma unroll
    for (int nt = 0; nt < 4; ++nt) {
        float lm = -1e30f;
#pragma unroll
        for (int mt = 0; mt < 4; ++mt)
#pragma unroll
            for (int j = 0; j < 4; ++j) lm = fmaxf(lm, acc[mt][nt][j]);
        redmax[nt * 256 + l16 * 16 + w * 4 + quad] = lm;
    }
    __syncthreads();

    float lse[4];
#pragma unroll
    for (int nt = 0; nt < 4; ++nt) {
        float gm = -1e30f;
#pragma unroll
        for (int i = 0; i < 16; ++i) gm = fmaxf(gm, redmax[nt * 256 + l16 * 16 + i]);
        float ls = 0.f;
#pragma unroll
        for (int mt = 0; mt < 4; ++mt)
#pragma unroll
            for (int j = 0; j < 4; ++j) ls += __expf(acc[mt][nt][j] - gm);
        redsum[nt * 256 + l16 * 16 + w * 4 + quad] = ls;
        lse[nt] = gm;
    }
    __syncthreads();

#pragma unroll
    for (int nt = 0; nt < 4; ++nt) {
        float tot = 0.f;
#pragma unroll
        for (int i = 0; i < 16; ++i) tot += redsum[nt * 256 + l16 * 16 + i];
        lse[nt] = lse[nt] + __logf(tot);
    }

#pragma unroll
    for (int mt = 0; mt < 4; ++mt) {
        const int mb = m0 + mt * 16 + quad * 4;
#pragma unroll
        for (int nt = 0; nt < 4; ++nt) {
            const int t = n0 + nt * 16 + l16;
#pragma unroll
            for (int j = 0; j < 4; ++j)
                out[(size_t)(mb + j) * T_LEN + t] = acc[mt][nt][j] - lse[nt];
        }
    }
}

extern "C" void kernel_launch(void* const* d_in, const int* in_sizes, int n_in,
                              void* d_out, int out_size, void* d_ws, size_t ws_size,
                              hipStream_t stream)
{
    (void)in_sizes; (void)n_in; (void)out_size; (void)ws_size;
    const float* x     = (const float*)d_in[0];
    const float* Wc    = (const float*)d_in[1];
    const float* bc    = (const float*)d_in[2];
    const float* Wt    = (const float*)d_in[3];
    const float* bt    = (const float*)d_in[4];
    const float* Ws    = (const float*)d_in[5];
    const float* bs    = (const float*)d_in[6];
    const float* Wskip = (const float*)d_in[7];
    const float* bskip = (const float*)d_in[8];
    const float* Wd    = (const float*)d_in[9];
    const float* bd    = (const float*)d_in[10];
    const float* Wp1   = (const float*)d_in[11];
    const float* bp1   = (const float*)d_in[12];
    const float* Wp2   = (const float*)d_in[13];
    const float* bp2   = (const float*)d_in[14];
    float* out = (float*)d_out;

    char* p = (char*)d_ws;
    unsigned short* Gt = (unsigned short*)p;    p += (size_t)T_LEN * KTOT * 2;   // 226.5 MB
    unsigned short* ht = (unsigned short*)p;    p += (size_t)T_LEN * SD * 2;     // 134 MB
    unsigned short* Wcomb = (unsigned short*)p; p += (size_t)SD * KTOT * 2;
    unsigned short* Wp2b = (unsigned short*)p;  p += (size_t)QD * SD * 2;
    unsigned short* Wg = (unsigned short*)p;    p += (size_t)NL * 64 * 96 * 2;
    unsigned short* Wdb = (unsigned short*)p;   p += (size_t)NL * RD * RD * 2;
    float* hbias = (float*)p;                   p += (size_t)SD * 4;

    // guarded hi/lo x buffers alias the ht region (dead before gemm1 writes ht):
    // 4 x (T+512)*32*2B = 33.7 MB < 134 MB
    char* q = (char*)ht;
    const size_t grows = (size_t)(T_LEN + 2 * GPAD) * RD;
    unsigned short* xahG = (unsigned short*)q;  q += grows * 2;
    unsigned short* xalG = (unsigned short*)q;  q += grows * 2;
    unsigned short* xbhG = (unsigned short*)q;  q += grows * 2;
    unsigned short* xblG = (unsigned short*)q;  q += grows * 2;
    unsigned short* xah = xahG + (size_t)GPAD * RD;
    unsigned short* xal = xalG + (size_t)GPAD * RD;
    unsigned short* xbh = xbhG + (size_t)GPAD * RD;
    unsigned short* xbl = xblG + (size_t)GPAD * RD;

    k_wcomb<<<(SD * KTOT + 255) / 256, 256, 0, stream>>>(Wp1, Wskip, Wcomb);
    k_hbias<<<1, 512, 0, stream>>>(Wp1, bp1, bskip, hbias);
    k_cvt<<<(QD * SD + 255) / 256, 256, 0, stream>>>(Wp2, Wp2b, QD * SD);
    {
        const int nprep = NL * 64 * 96 + NL * RD * RD;
        k_wprep<<<(nprep + 255) / 256, 256, 0, stream>>>(Wt, Ws, Wd, Wg, Wdb);
    }
    k_conv_init<<<T_LEN / 256, 256, 0, stream>>>(x, Wc, bc, xahG, xalG, xbhG);

    static const int dil[NL] = {1, 2, 4, 8, 16, 32, 64, 128, 256,
                                1, 2, 4, 8, 16, 32, 64, 128, 256,
                                1, 2, 4, 8, 16, 32, 64, 128, 256};
    const unsigned short* curh = xah;
    const unsigned short* curl = xal;
    unsigned short* nxth = xbh;
    unsigned short* nxtl = xbl;
    for (int i = 0; i < NL; ++i) {
        k_layer_stage<<<T_LEN / 128, 256, 0, stream>>>(
            curh, curl, nxth, nxtl, Gt,
            Wg + (size_t)i * 64 * 96,
            Wdb + (size_t)i * RD * RD,
            bt + (size_t)i * RD,
            bs + (size_t)i * RD,
            bd + (size_t)i * RD,
            dil[i], i);
        { unsigned short* th = (unsigned short*)curh; curh = nxth; nxth = th; }
        { unsigned short* tl = (unsigned short*)curl; curl = nxtl; nxtl = tl; }
    }

    k_gemm1<<<4 * (T_LEN / 128), 256, 0, stream>>>(Wcomb, Gt, hbias, ht);
    k_gemm2_lsm<<<T_LEN / 64, 256, 0, stream>>>(Wp2b, ht, bp2, out);
}

// Round 12
// 869.598 us; speedup vs baseline: 1.2109x; 1.0299x over previous
//
#include <hip/hip_runtime.h>

#define T_LEN 131072
#define RD 32
#define SD 512
#define QD 256
#define NL 27
#define KTOT (NL * RD)   // 864
#define GPAD 256         // guard rows (zeros) on each side of x-hi buffers

typedef __attribute__((ext_vector_type(8))) short short8;
typedef __attribute__((ext_vector_type(4))) float floatx4;

__device__ __forceinline__ unsigned short f2bf(float f) {
    union { float f; unsigned int i; } v; v.f = f;
    unsigned int r = v.i + 0x7fffu + ((v.i >> 16) & 1u);  // RNE
    return (unsigned short)(r >> 16);
}

__device__ __forceinline__ float bf2f(unsigned short h) {
    union { unsigned int i; float f; } u; u.i = (unsigned int)h << 16;
    return u.f;
}

__device__ __forceinline__ void gload_lds16(const void* g, void* l) {
    __builtin_amdgcn_global_load_lds(
        (const __attribute__((address_space(1))) unsigned int*)g,
        (__attribute__((address_space(3))) unsigned int*)l, 16, 0, 0);
}

// ---------------- initial conv: [1,T] -> hi/lo bf16 split; zero hi guards ----------------
__global__ __launch_bounds__(256)
void k_conv_init(const float* __restrict__ x, const float* __restrict__ Wc,
                 const float* __restrict__ bc,
                 unsigned short* __restrict__ xahG, unsigned short* __restrict__ xalG,
                 unsigned short* __restrict__ xbhG)
{
    const int gid = blockIdx.x * 256 + threadIdx.x;

    // zero the hi-array guard regions (taps read them; zeros == conv padding)
    if (gid < 4 * GPAD * RD) {
        const int region = gid >> 13;           // GPAD*RD = 8192
        const int idx = gid & (GPAD * RD - 1);
        unsigned short* hg;
        const size_t post = (size_t)(GPAD + T_LEN) * RD;
        switch (region) {
            case 0:  hg = xahG;        break;
            case 1:  hg = xahG + post; break;
            case 2:  hg = xbhG;        break;
            default: hg = xbhG + post; break;
        }
        hg[idx] = 0;
    }

    const int t = gid;
    const float xm = (t > 0) ? x[t - 1] : 0.f;
    const float x0 = x[t];
    const float xp = (t < T_LEN - 1) ? x[t + 1] : 0.f;
    unsigned short* rowh = xahG + (size_t)(GPAD + t) * RD;
    unsigned short* rowl = xalG + (size_t)(GPAD + t) * RD;
#pragma unroll
    for (int o = 0; o < RD; ++o) {
        const float v = bc[o] + Wc[o * 3 + 0] * xm + Wc[o * 3 + 1] * x0 + Wc[o * 3 + 2] * xp;
        const unsigned short h = f2bf(v);
        rowh[o] = h;
        rowl[o] = f2bf(v - bf2f(h));
    }
}

// ---------------- weight prep ----------------
__global__ __launch_bounds__(256)
void k_wprep(const float* __restrict__ Wt, const float* __restrict__ Ws,
             const float* __restrict__ Wd,
             unsigned short* __restrict__ Wg, unsigned short* __restrict__ Wdb)
{
    const int idx = blockIdx.x * 256 + threadIdx.x;
    const int n1 = NL * 64 * 96;
    const int n2 = NL * RD * RD;
    if (idx < n1) {
        const int l = idx / (64 * 96);
        const int rem = idx % (64 * 96);
        const int m = rem / 96;
        const int k = rem % 96;
        const int j = k / 32;
        const int c = k % 32;
        float v;
        if (m < 32) v = Wt[(((size_t)l * RD + m) * RD + c) * 3 + j];
        else        v = Ws[(((size_t)l * RD + (m - 32)) * RD + c) * 3 + j];
        Wg[idx] = f2bf(v);
    } else if (idx < n1 + n2) {
        const int i2 = idx - n1;
        Wdb[i2] = f2bf(Wd[i2]);
    }
}

// ---------------- single residual layer: hi/lo bf16 x, per-wave async, NO barriers ----------------
// (R9/R11 known-good: ~22 us/layer)
__global__ __launch_bounds__(256, 4)
void k_layer_stage(const unsigned short* __restrict__ xinh,   // guarded + GPAD
                   const unsigned short* __restrict__ xinl,   // + GPAD (rows [0,T) used)
                   unsigned short* __restrict__ xouth,
                   unsigned short* __restrict__ xoutl,
                   unsigned short* __restrict__ Gt,           // [NL][T][32]
                   const unsigned short* __restrict__ Wg,
                   const unsigned short* __restrict__ Wdb,
                   const float* __restrict__ bt, const float* __restrict__ bs,
                   const float* __restrict__ bd, int d, int layer)
{
    __shared__ unsigned short bandsL[3][128 * 32];  // 24 KB (hi taps)
    __shared__ unsigned short loL[128 * 32];        // 8 KB (lo center)
    __shared__ unsigned short gtileL[128 * 32];     // 8 KB -> 40 KB total

    const int tid = threadIdx.x;
    const int lane = tid & 63;
    const int w = tid >> 6;
    const int quad = lane >> 4;
    const int l16 = lane & 15;
    const int rbase = w * 32;
    const bool last = (layer == NL - 1);
    const floatx4 vzero = {0.f, 0.f, 0.f, 0.f};

    const int r16c = lane >> 2;
    const int scB = (lane & 3) ^ ((lane >> 3) & 3);
    const long long gbase = (long long)blockIdx.x * 128 + rbase;

    // ---- issue hi band DMAs (6) ----
#pragma unroll
    for (int j = 0; j < 3; ++j) {
        const long long b0 = gbase + (long long)(j - 1) * d;
#pragma unroll
        for (int i = 0; i < 2; ++i)
            gload_lds16(xinh + (b0 + i * 16 + r16c) * RD + scB * 8,
                        &bandsL[j][(rbase + i * 16) * 32]);
    }
    asm volatile("" ::: "memory");   // pin: bands issue before lo DMAs

    // ---- issue lo center DMAs (2) + counted wait ----
    if (!last) {
#pragma unroll
        for (int i = 0; i < 2; ++i)
            gload_lds16(xinl + (gbase + i * 16 + r16c) * RD + scB * 8,
                        &loL[(rbase + i * 16) * 32]);
        asm volatile("s_waitcnt vmcnt(2)" ::: "memory");  // 6 bands done, lo in flight
    } else {
        asm volatile("s_waitcnt vmcnt(0)" ::: "memory");
    }

    short8 afr[3][4];
#pragma unroll
    for (int j = 0; j < 3; ++j)
#pragma unroll
        for (int mt = 0; mt < 4; ++mt)
            afr[j][mt] = *reinterpret_cast<const short8*>(
                Wg + (size_t)(mt * 16 + l16) * 96 + j * 32 + quad * 8);

    floatx4 acc[4][2];
#pragma unroll
    for (int mt = 0; mt < 4; ++mt)
#pragma unroll
        for (int nt = 0; nt < 2; ++nt) acc[mt][nt] = vzero;

#pragma unroll
    for (int nt = 0; nt < 2; ++nt) {
        const int rloc = rbase + nt * 16 + l16;
        const int key2 = (rloc >> 1) & 3;
#pragma unroll
        for (int j = 0; j < 3; ++j) {
            const short8 bb = *reinterpret_cast<const short8*>(
                &bandsL[j][rloc * 32 + ((quad ^ key2) * 8)]);
#pragma unroll
            for (int mt = 0; mt < 4; ++mt)
                acc[mt][nt] = __builtin_amdgcn_mfma_f32_16x16x32_bf16(
                    afr[j][mt], bb, acc[mt][nt], 0, 0, 0);
        }
    }

    if (!last) asm volatile("s_waitcnt vmcnt(0)" ::: "memory");  // lo ready

#pragma unroll
    for (int nt = 0; nt < 2; ++nt) {
        const int rloc = rbase + nt * 16 + l16;
        const int key2 = (rloc >> 1) & 3;
        const long long t = (long long)blockIdx.x * 128 + rloc;
#pragma unroll
        for (int pair = 0; pair < 2; ++pair) {
            const floatx4 bt4 = *reinterpret_cast<const floatx4*>(bt + pair * 16 + quad * 4);
            const floatx4 bs4 = *reinterpret_cast<const floatx4*>(bs + pair * 16 + quad * 4);
            ushort4 u;
            unsigned short us[4];
#pragma unroll
            for (int r = 0; r < 4; ++r) {
                const float a1 = acc[pair][nt][r] + bt4[r];
                const float a2 = acc[2 + pair][nt][r] + bs4[r];
                const float th = 1.f - __fdividef(2.f, __expf(2.f * a1) + 1.f);
                const float sg = __fdividef(1.f, 1.f + __expf(-a2));
                us[r] = f2bf(th * sg);
            }
            u.x = us[0]; u.y = us[1]; u.z = us[2]; u.w = us[3];
            const int cbase = pair * 16 + quad * 4;
            if (!last) {
                const int colS = (pair * 2 + (quad >> 1)) ^ key2;
                *reinterpret_cast<ushort4*>(
                    &gtileL[rloc * 32 + colS * 8 + (quad & 1) * 4]) = u;
            }
            *reinterpret_cast<ushort4*>(
                Gt + ((size_t)layer * T_LEN + t) * RD + cbase) = u;
        }
    }

    if (!last) {
        short8 ad[2];
#pragma unroll
        for (int mt = 0; mt < 2; ++mt)
            ad[mt] = *reinterpret_cast<const short8*>(
                Wdb + (size_t)(mt * 16 + l16) * RD + quad * 8);

#pragma unroll
        for (int nt = 0; nt < 2; ++nt) {
            const int rloc = rbase + nt * 16 + l16;
            const int key2 = (rloc >> 1) & 3;
            const long long t = (long long)blockIdx.x * 128 + rloc;
            const short8 bg = *reinterpret_cast<const short8*>(
                &gtileL[rloc * 32 + ((quad ^ key2) * 8)]);
#pragma unroll
            for (int mt = 0; mt < 2; ++mt) {
                const floatx4 a2v = __builtin_amdgcn_mfma_f32_16x16x32_bf16(
                    ad[mt], bg, vzero, 0, 0, 0);
                const int m = mt * 16 + quad * 4;
                // hi center == band j=1; lo from loL; same chunk addressing as gtile
                const int colS2 = (mt * 2 + (quad >> 1)) ^ key2;
                const int off = rloc * 32 + colS2 * 8 + (quad & 1) * 4;
                const ushort4 hi4 = *reinterpret_cast<const ushort4*>(&bandsL[1][off]);
                const ushort4 lo4 = *reinterpret_cast<const ushort4*>(&loL[off]);
                const floatx4 bd4 = *reinterpret_cast<const floatx4*>(bd + m);
                float o0 = a2v[0] + bd4[0] + bf2f(hi4.x) + bf2f(lo4.x);
                float o1 = a2v[1] + bd4[1] + bf2f(hi4.y) + bf2f(lo4.y);
                float o2 = a2v[2] + bd4[2] + bf2f(hi4.z) + bf2f(lo4.z);
                float o3 = a2v[3] + bd4[3] + bf2f(hi4.w) + bf2f(lo4.w);
                ushort4 oh, ol;
                oh.x = f2bf(o0); ol.x = f2bf(o0 - bf2f(oh.x));
                oh.y = f2bf(o1); ol.y = f2bf(o1 - bf2f(oh.y));
                oh.z = f2bf(o2); ol.z = f2bf(o2 - bf2f(oh.z));
                oh.w = f2bf(o3); ol.w = f2bf(o3 - bf2f(oh.w));
                *reinterpret_cast<ushort4*>(xouth + (size_t)t * RD + m) = oh;
                *reinterpret_cast<ushort4*>(xoutl + (size_t)t * RD + m) = ol;
            }
        }
    }
}

// ---------------- Wcomb (chunk-major [27][512][32]) ----------------
// Restructured for reuse: each thread computes 8 m-outputs for one (l,c) --
// the Wskip element is loaded once per j and reused 8x; the 8 Wp1 streams
// are sequential in j (perfect line reuse). ~8x less L2 traffic than the
// 1-output-per-thread version. Per-output summation is ascending-j in a
// single thread -> BIT-IDENTICAL results.
__global__ __launch_bounds__(256)
void k_wcomb(const float* __restrict__ Wp1, const float* __restrict__ Wskip,
             unsigned short* __restrict__ Wcomb)
{
    const int idx = blockIdx.x * 256 + threadIdx.x;   // 216*256 = 55296 exact
    const int c = idx & 31;
    const int t2 = idx >> 5;
    const int l = t2 % NL;
    const int mg = t2 / NL;            // 0..63
    const int m0 = mg * 8;

    const float* wskp = Wskip + (size_t)l * SD * RD + c;   // + j*RD per iter
    const float* wp = Wp1 + (size_t)m0 * SD;               // 8 rows, + j per iter

    float acc[8];
#pragma unroll
    for (int i = 0; i < 8; ++i) acc[i] = 0.f;

    for (int j = 0; j < SD; ++j) {
        const float wv = wskp[(size_t)j * RD];
#pragma unroll
        for (int i = 0; i < 8; ++i)
            acc[i] += wp[(size_t)i * SD + j] * wv;
    }

#pragma unroll
    for (int i = 0; i < 8; ++i)
        Wcomb[((size_t)l * SD + m0 + i) * RD + c] = f2bf(acc[i]);
}

// ---------------- hbias: parallel (128 blocks, one wave per m-row) ----------------
// sb[j] summed over l ascending (same order as before); the per-row dot is
// lane-partitioned + shuffle-reduced (order differs from serial by fp32
// rounding ~1e-7 relative -- 5 orders below output absmax).
__global__ __launch_bounds__(256)
void k_hbias(const float* __restrict__ Wp1, const float* __restrict__ bp1,
             const float* __restrict__ bskip, float* __restrict__ hbias)
{
    __shared__ float sb[SD];
    const int tid = threadIdx.x;
    for (int jj = tid; jj < SD; jj += 256) {
        float s = 0.f;
        for (int l = 0; l < NL; ++l) s += bskip[l * SD + jj];
        sb[jj] = s;
    }
    __syncthreads();

    const int w = tid >> 6;
    const int lane = tid & 63;
    const int m = blockIdx.x * 4 + w;
    const float* r = Wp1 + (size_t)m * SD;
    float pf = 0.f;
#pragma unroll
    for (int it = 0; it < 8; ++it) {
        const int j = it * 64 + lane;
        pf += r[j] * sb[j];
    }
#pragma unroll
    for (int off = 32; off > 0; off >>= 1) pf += __shfl_down(pf, off, 64);
    if (lane == 0) hbias[m] = bp1[m] + pf;
}

// ---------------- fp32 -> bf16 cast ----------------
__global__ __launch_bounds__(256)
void k_cvt(const float* __restrict__ src, unsigned short* __restrict__ dst, int n)
{
    const int i = blockIdx.x * 256 + threadIdx.x;
    if (i < n) dst[i] = f2bf(src[i]);
}

// ---------------- GEMM1, BK=64 (R6/R8/R11 known-good: ~166 us) ----------------
__global__ __launch_bounds__(256)
void k_gemm1(const unsigned short* __restrict__ A,   // Wcomb [27][512][32]
             const unsigned short* __restrict__ B,   // Gt [27][T][32]
             const float* __restrict__ hbias,
             unsigned short* __restrict__ ht)        // [16][T][32]
{
    __shared__ unsigned short ldsA[2][128 * 32];  // 16 KB
    __shared__ unsigned short ldsB[2][128 * 32];  // 16 KB
    const int tid = threadIdx.x;
    const int lane = tid & 63;
    const int w = tid >> 6;
    const int wm = w & 1;
    const int wn = w >> 1;
    const int quad = lane >> 4;
    const int l16 = lane & 15;

    const int g = blockIdx.x;
    const int m0 = ((g >> 3) & 3) * 128;
    const int n0 = ((g & 7) + 8 * (g >> 5)) * 128;

    const int r4 = lane >> 2;
    const int c4 = lane & 3;
    const int srcc = c4 ^ ((r4 >> 1) & 3);
    const int swz = (l16 >> 1) & 3;

    floatx4 acc[4][4];
    const floatx4 vzero = {0.f, 0.f, 0.f, 0.f};
#pragma unroll
    for (int mt = 0; mt < 4; ++mt)
#pragma unroll
        for (int nt = 0; nt < 4; ++nt) acc[mt][nt] = vzero;

    const unsigned short* pA = A + (size_t)(m0 + r4) * RD + srcc * 8;
    const unsigned short* pB = B + (size_t)(n0 + r4) * RD + srcc * 8;

    for (int kc2 = 0; kc2 < 13; ++kc2) {
#pragma unroll
        for (int s = 0; s < 2; ++s) {
            const int kc = kc2 * 2 + s;
#pragma unroll
            for (int c = 0; c < 2; ++c) {
                const int row = w * 32 + c * 16;
                gload_lds16(pA + ((size_t)kc * SD + row) * RD, &ldsA[s][row * 32]);
                gload_lds16(pB + ((size_t)kc * T_LEN + row) * RD, &ldsB[s][row * 32]);
            }
        }
        __syncthreads();

#pragma unroll
        for (int s = 0; s < 2; ++s) {
            short8 afr[4], bfr[4];
#pragma unroll
            for (int mt = 0; mt < 4; ++mt)
                afr[mt] = *reinterpret_cast<const short8*>(
                    &ldsA[s][(wm * 64 + mt * 16 + l16) * 32 + (quad ^ swz) * 8]);
#pragma unroll
            for (int nt = 0; nt < 4; ++nt)
                bfr[nt] = *reinterpret_cast<const short8*>(
                    &ldsB[s][(wn * 64 + nt * 16 + l16) * 32 + (quad ^ swz) * 8]);
#pragma unroll
            for (int mt = 0; mt < 4; ++mt)
#pragma unroll
                for (int nt = 0; nt < 4; ++nt)
                    acc[mt][nt] = __builtin_amdgcn_mfma_f32_16x16x32_bf16(
                        afr[mt], bfr[nt], acc[mt][nt], 0, 0, 0);
        }
        __syncthreads();
    }
    // tail: chunk 26
    {
        const int kc = 26;
#pragma unroll
        for (int c = 0; c < 2; ++c) {
            const int row = w * 32 + c * 16;
            gload_lds16(pA + ((size_t)kc * SD + row) * RD, &ldsA[0][row * 32]);
            gload_lds16(pB + ((size_t)kc * T_LEN + row) * RD, &ldsB[0][row * 32]);
        }
        __syncthreads();
        short8 afr[4], bfr[4];
#pragma unroll
        for (int mt = 0; mt < 4; ++mt)
            afr[mt] = *reinterpret_cast<const short8*>(
                &ldsA[0][(wm * 64 + mt * 16 + l16) * 32 + (quad ^ swz) * 8]);
#pragma unroll
        for (int nt = 0; nt < 4; ++nt)
            bfr[nt] = *reinterpret_cast<const short8*>(
                &ldsB[0][(wn * 64 + nt * 16 + l16) * 32 + (quad ^ swz) * 8]);
#pragma unroll
        for (int mt = 0; mt < 4; ++mt)
#pragma unroll
            for (int nt = 0; nt < 4; ++nt)
                acc[mt][nt] = __builtin_amdgcn_mfma_f32_16x16x32_bf16(
                    afr[mt], bfr[nt], acc[mt][nt], 0, 0, 0);
    }

#pragma unroll
    for (int mt = 0; mt < 4; ++mt) {
        const int m = m0 + wm * 64 + mt * 16 + quad * 4;
        const floatx4 hb = *reinterpret_cast<const floatx4*>(hbias + m);
        const size_t chunkbase = (size_t)(m >> 5) * T_LEN;
        const int mc = m & 31;
#pragma unroll
        for (int nt = 0; nt < 4; ++nt) {
            const int t = n0 + wn * 64 + nt * 16 + l16;
            ushort4 st;
            float v;
            v = acc[mt][nt][0] + hb[0]; st.x = f2bf(v > 0.f ? v : 0.f);
            v = acc[mt][nt][1] + hb[1]; st.y = f2bf(v > 0.f ? v : 0.f);
            v = acc[mt][nt][2] + hb[2]; st.z = f2bf(v > 0.f ? v : 0.f);
            v = acc[mt][nt][3] + hb[3]; st.w = f2bf(v > 0.f ? v : 0.f);
            *reinterpret_cast<ushort4*>(ht + (chunkbase + t) * RD + mc) = st;
        }
    }
}

// ---------------- GEMM2 + fused log_softmax, 4-deep B staging (R7-R11: kept) ----------------
__global__ __launch_bounds__(256)
void k_gemm2_lsm(const unsigned short* __restrict__ A,  // Wp2b [256][512] bf16
                 const unsigned short* __restrict__ B,  // ht [16][T][32] bf16
                 const float* __restrict__ bp2,
                 float* __restrict__ out)               // [256][T] fp32
{
    __shared__ unsigned short ldsB[4][64 * 32];  // 16 KB
    __shared__ float redmax[4 * 16 * 16];
    __shared__ float redsum[4 * 16 * 16];
    const int tid = threadIdx.x;
    const int lane = tid & 63;
    const int w = tid >> 6;
    const int quad = lane >> 4;
    const int l16 = lane & 15;
    const int m0 = w * 64;
    const int n0 = blockIdx.x * 64;

    const int r4 = lane >> 2;
    const int c4 = lane & 3;
    const int srcc = c4 ^ ((r4 >> 1) & 3);
    const int swz = (l16 >> 1) & 3;

    const unsigned short* ab[4];
#pragma unroll
    for (int mt = 0; mt < 4; ++mt)
        ab[mt] = A + (size_t)(m0 + mt * 16 + l16) * SD + quad * 8;

    const unsigned short* pB = B + (size_t)(n0 + w * 16 + r4) * RD + srcc * 8;

    floatx4 acc[4][4];
    const floatx4 vzero = {0.f, 0.f, 0.f, 0.f};
#pragma unroll
    for (int mt = 0; mt < 4; ++mt)
#pragma unroll
        for (int nt = 0; nt < 4; ++nt) acc[mt][nt] = vzero;

    for (int kc4 = 0; kc4 < 4; ++kc4) {
#pragma unroll
        for (int s = 0; s < 4; ++s)
            gload_lds16(pB + (size_t)(kc4 * 4 + s) * T_LEN * RD,
                        &ldsB[s][(w * 16) * 32]);
        __syncthreads();

#pragma unroll
        for (int s = 0; s < 4; ++s) {
            const int kc = kc4 * 4 + s;
            short8 afr[4];
#pragma unroll
            for (int mt = 0; mt < 4; ++mt)
                afr[mt] = *reinterpret_cast<const short8*>(ab[mt] + kc * 32);
            short8 bfr[4];
#pragma unroll
            for (int nt = 0; nt < 4; ++nt)
                bfr[nt] = *reinterpret_cast<const short8*>(
                    &ldsB[s][(nt * 16 + l16) * 32 + (quad ^ swz) * 8]);
#pragma unroll
            for (int mt = 0; mt < 4; ++mt)
#pragma unroll
                for (int nt = 0; nt < 4; ++nt)
                    acc[mt][nt] = __builtin_amdgcn_mfma_f32_16x16x32_bf16(
                        afr[mt], bfr[nt], acc[mt][nt], 0, 0, 0);
        }
        __syncthreads();
    }

#pragma unroll
    for (int mt = 0; mt < 4; ++mt) {
        const int mb = m0 + mt * 16 + quad * 4;
        const floatx4 bz = *reinterpret_cast<const floatx4*>(bp2 + mb);
#pragma unroll
        for (int nt = 0; nt < 4; ++nt)
#pragma unroll
            for (int j = 0; j < 4; ++j) acc[mt][nt][j] += bz[j];
    }

#pragma unroll
    for (int nt = 0; nt < 4; ++nt) {
        float lm = -1e30f;
#pragma unroll
        for (int mt = 0; mt < 4; ++mt)
#pragma unroll
            for (int j = 0; j < 4; ++j) lm = fmaxf(lm, acc[mt][nt][j]);
        redmax[nt * 256 + l16 * 16 + w * 4 + quad] = lm;
    }
    __syncthreads();

    float lse[4];
#pragma unroll
    for (int nt = 0; nt < 4; ++nt) {
        float gm = -1e30f;
#pragma unroll
        for (int i = 0; i < 16; ++i) gm = fmaxf(gm, redmax[nt * 256 + l16 * 16 + i]);
        float ls = 0.f;
#pragma unroll
        for (int mt = 0; mt < 4; ++mt)
#pragma unroll
            for (int j = 0; j < 4; ++j) ls += __expf(acc[mt][nt][j] - gm);
        redsum[nt * 256 + l16 * 16 + w * 4 + quad] = ls;
        lse[nt] = gm;
    }
    __syncthreads();

#pragma unroll
    for (int nt = 0; nt < 4; ++nt) {
        float tot = 0.f;
#pragma unroll
        for (int i = 0; i < 16; ++i) tot += redsum[nt * 256 + l16 * 16 + i];
        lse[nt] = lse[nt] + __logf(tot);
    }

#pragma unroll
    for (int mt = 0; mt < 4; ++mt) {
        const int mb = m0 + mt * 16 + quad * 4;
#pragma unroll
        for (int nt = 0; nt < 4; ++nt) {
            const int t = n0 + nt * 16 + l16;
#pragma unroll
            for (int j = 0; j < 4; ++j)
                out[(size_t)(mb + j) * T_LEN + t] = acc[mt][nt][j] - lse[nt];
        }
    }
}

extern "C" void kernel_launch(void* const* d_in, const int* in_sizes, int n_in,
                              void* d_out, int out_size, void* d_ws, size_t ws_size,
                              hipStream_t stream)
{
    (void)in_sizes; (void)n_in; (void)out_size; (void)ws_size;
    const float* x     = (const float*)d_in[0];
    const float* Wc    = (const float*)d_in[1];
    const float* bc    = (const float*)d_in[2];
    const float* Wt    = (const float*)d_in[3];
    const float* bt    = (const float*)d_in[4];
    const float* Ws    = (const float*)d_in[5];
    const float* bs    = (const float*)d_in[6];
    const float* Wskip = (const float*)d_in[7];
    const float* bskip = (const float*)d_in[8];
    const float* Wd    = (const float*)d_in[9];
    const float* bd    = (const float*)d_in[10];
    const float* Wp1   = (const float*)d_in[11];
    const float* bp1   = (const float*)d_in[12];
    const float* Wp2   = (const float*)d_in[13];
    const float* bp2   = (const float*)d_in[14];
    float* out = (float*)d_out;

    char* p = (char*)d_ws;
    unsigned short* Gt = (unsigned short*)p;    p += (size_t)T_LEN * KTOT * 2;   // 226.5 MB
    unsigned short* ht = (unsigned short*)p;    p += (size_t)T_LEN * SD * 2;     // 134 MB
    unsigned short* Wcomb = (unsigned short*)p; p += (size_t)SD * KTOT * 2;
    unsigned short* Wp2b = (unsigned short*)p;  p += (size_t)QD * SD * 2;
    unsigned short* Wg = (unsigned short*)p;    p += (size_t)NL * 64 * 96 * 2;
    unsigned short* Wdb = (unsigned short*)p;   p += (size_t)NL * RD * RD * 2;
    float* hbias = (float*)p;                   p += (size_t)SD * 4;

    // guarded hi/lo x buffers alias the ht region (dead before gemm1 writes ht):
    // 4 x (T+512)*32*2B = 33.7 MB < 134 MB
    char* q = (char*)ht;
    const size_t grows = (size_t)(T_LEN + 2 * GPAD) * RD;
    unsigned short* xahG = (unsigned short*)q;  q += grows * 2;
    unsigned short* xalG = (unsigned short*)q;  q += grows * 2;
    unsigned short* xbhG = (unsigned short*)q;  q += grows * 2;
    unsigned short* xblG = (unsigned short*)q;  q += grows * 2;
    unsigned short* xah = xahG + (size_t)GPAD * RD;
    unsigned short* xal = xalG + (size_t)GPAD * RD;
    unsigned short* xbh = xbhG + (size_t)GPAD * RD;
    unsigned short* xbl = xblG + (size_t)GPAD * RD;

    k_wcomb<<<(NL * 32 * 64) / 256, 256, 0, stream>>>(Wp1, Wskip, Wcomb);   // 216 blocks
    k_hbias<<<SD / 4, 256, 0, stream>>>(Wp1, bp1, bskip, hbias);            // 128 blocks
    k_cvt<<<(QD * SD + 255) / 256, 256, 0, stream>>>(Wp2, Wp2b, QD * SD);
    {
        const int nprep = NL * 64 * 96 + NL * RD * RD;
        k_wprep<<<(nprep + 255) / 256, 256, 0, stream>>>(Wt, Ws, Wd, Wg, Wdb);
    }
    k_conv_init<<<T_LEN / 256, 256, 0, stream>>>(x, Wc, bc, xahG, xalG, xbhG);

    static const int dil[NL] = {1, 2, 4, 8, 16, 32, 64, 128, 256,
                                1, 2, 4, 8, 16, 32, 64, 128, 256,
                                1, 2, 4, 8, 16, 32, 64, 128, 256};
    const unsigned short* curh = xah;
    const unsigned short* curl = xal;
    unsigned short* nxth = xbh;
    unsigned short* nxtl = xbl;
    for (int i = 0; i < NL; ++i) {
        k_layer_stage<<<T_LEN / 128, 256, 0, stream>>>(
            curh, curl, nxth, nxtl, Gt,
            Wg + (size_t)i * 64 * 96,
            Wdb + (size_t)i * RD * RD,
            bt + (size_t)i * RD,
            bs + (size_t)i * RD,
            bd + (size_t)i * RD,
            dil[i], i);
        { unsigned short* th = (unsigned short*)curh; curh = nxth; nxth = th; }
        { unsigned short* tl = (unsigned short*)curl; curl = nxtl; nxtl = tl; }
    }

    k_gemm1<<<4 * (T_LEN / 128), 256, 0, stream>>>(Wcomb, Gt, hbias, ht);
    k_gemm2_lsm<<<T_LEN / 64, 256, 0, stream>>>(Wp2b, ht, bp2, out);
}